// Round 24
// baseline (408.637 us; speedup 1.0000x reference)
//
#include <hip/hip_runtime.h>
#include <stdint.h>

#define BATCH 8
#define NPTS  16384
#define BN    (BATCH * NPTS)
#define CH    512                 // points per chunk (cmin granularity)
#define NCH   (NPTS / CH)         // 32
#define QPB   256                 // 4 waves x 64 queries in sweep1
#define MARGIN 3.0e-3f            // > 2*delta_worst (2.6e-3), deterministic bound
#define QCAP  (1u << 20)          // queue capacity (4 MiB in dead enc region)

typedef float f32x16 __attribute__((ext_vector_type(16)));
typedef short s16x8  __attribute__((ext_vector_type(8)));

__device__ __forceinline__ uint16_t bfr(float x) {
    uint32_t u = __float_as_uint(x);
    return (uint16_t)((u + 0x7FFFu + ((u >> 16) & 1u)) >> 16);
}
__device__ __forceinline__ float bff(uint16_t s) {
    return __uint_as_float(((uint32_t)s) << 16);
}
__device__ __forceinline__ void split2(float v, uint16_t* a, uint16_t* b) {
    *a = bfr(v); *b = bfr(v - bff(*a));
}
__device__ __forceinline__ uint32_t pk2(uint16_t lo, uint16_t hi) {
    return (uint32_t)lo | ((uint32_t)hi << 16);
}
__device__ __forceinline__ uint32_t key32(float d) {
    uint32_t b = __float_as_uint(d);
    return (b & 0x80000000u) ? ~b : (b | 0x80000000u);
}
__device__ __forceinline__ float dec32(uint32_t k) {
    return __uint_as_float((k & 0x80000000u) ? (k ^ 0x80000000u) : ~k);
}

#define MIN3(a, b, c) fminf(fminf((a), (b)), (c))

__device__ __forceinline__ float fold16(const f32x16 a) {
    const float u0 = MIN3(a[0],  a[1],  a[2]);
    const float u1 = MIN3(a[3],  a[4],  a[5]);
    const float u2 = MIN3(a[6],  a[7],  a[8]);
    const float u3 = MIN3(a[9],  a[10], a[11]);
    const float u4 = MIN3(a[12], a[13], a[14]);
    const float v0 = MIN3(u0, u1, a[15]);
    const float v1 = MIN3(u2, u3, u4);
    return fminf(v0, v1);
}

// ---- enc: 16 bf16 K-slots (double-split) + y4 fast-eval array ----
__global__ __launch_bounds__(256) void enc_kernel(
    const float* __restrict__ Y, uint4* __restrict__ enc,
    float4* __restrict__ y4)
{
#pragma clang fp contract(off)
    const int g = blockIdx.x * 256 + threadIdx.x;     // 0..BN-1
    const int b = g >> 14, p = g & (NPTS - 1);
    const float y0 = Y[(size_t)g * 3 + 0];
    const float y1 = Y[(size_t)g * 3 + 1];
    const float y2 = Y[(size_t)g * 3 + 2];
    const float ys = (y0 * y0 + y1 * y1) + y2 * y2;   // np order
    uint16_t Ya, Yb; split2(ys, &Ya, &Yb);
    uint16_t H0, M0; split2(-2.0f * y0, &H0, &M0);
    uint16_t H1, M1; split2(-2.0f * y1, &H1, &M1);
    uint16_t H2, M2; split2(-2.0f * y2, &H2, &M2);
    const uint16_t ONE = 0x3F80;
    const int ch = p >> 9, pp = p & (CH - 1);
    const size_t base = (size_t)(b * NCH + ch) * (2 * CH) + pp;
    enc[base]      = make_uint4(pk2(ONE, ONE), pk2(Ya, Yb), pk2(H0, M0), pk2(H0, M0));
    enc[base + CH] = make_uint4(pk2(H1, M1), pk2(H1, M1), pk2(H2, M2), pk2(H2, M2));
    y4[g] = make_float4(y0, y1, y2, ys);
}

#define STAGE(c, buf) { \
        const uint4* src_ = ep + (size_t)(c) * (2 * CH); \
        _Pragma("unroll") \
        for (int i_ = 0; i_ < 4; ++i_) \
            __builtin_amdgcn_global_load_lds( \
                (const __attribute__((address_space(1))) void*)(src_ + i_ * 256 + tid), \
                (__attribute__((address_space(3))) void*)&lds[buf][i_ * 256 + tid], \
                16, 0, 0); \
    }

#define MKQFR(dst, qq) { \
        const float* xp = Xp + (size_t)(qq) * 3; \
        const float x0 = xp[0], x1 = xp[1], x2 = xp[2]; \
        const float xs = (x0 * x0 + x1 * x1) + x2 * x2; \
        uint16_t Xa, Xb; split2(xs, &Xa, &Xb); \
        uint16_t h0, m0; split2(x0, &h0, &m0); \
        uint16_t h1, m1; split2(x1, &h1, &m1); \
        uint16_t h2, m2; split2(x2, &h2, &m2); \
        const uint16_t ONE = 0x3F80; \
        if (hi == 0) { \
            dst[0]=(short)Xa; dst[1]=(short)Xb; dst[2]=(short)ONE; dst[3]=(short)ONE; \
            dst[4]=(short)h0; dst[5]=(short)h0; dst[6]=(short)m0;  dst[7]=(short)m0; \
        } else { \
            dst[0]=(short)h1; dst[1]=(short)h1; dst[2]=(short)m1;  dst[3]=(short)m1; \
            dst[4]=(short)h2; dst[5]=(short)h2; dst[6]=(short)m2;  dst[7]=(short)m2; \
        } }

// ===== sweep1: per-query approx min (mkey) + per-(query,chunk) min (cmin) =====
__global__ __launch_bounds__(256, 4) void nn_sweep1(
    const float* __restrict__ Xp, const uint4* __restrict__ encp,
    uint32_t* __restrict__ mkey, uint16_t* __restrict__ cmin16)
{
#pragma clang fp contract(off)
    __shared__ uint4 lds[2][2 * CH];                   // 2 x 16 KB

    const int tid = threadIdx.x;
    const int l   = tid & 63;
    const int wv  = tid >> 6;
    const int col = l & 31;
    const int hi  = l >> 5;

    const int g     = blockIdx.x;
    const int batch = g & 7;
    const int kh    = (g >> 3) & 1;
    const int xblk  = g >> 4;                          // 0..63

    const uint4* ep = encp + (size_t)batch * (NCH * 2 * CH);
    const int bofs  = batch * NPTS;
    const int qbase = bofs + xblk * QPB + wv * 64;     // batch-global query base
    const int c0 = kh * (NCH / 2), c1 = c0 + NCH / 2;  // 16 chunks each

    const f32x16 zf = {0.f,0.f,0.f,0.f,0.f,0.f,0.f,0.f,
                       0.f,0.f,0.f,0.f,0.f,0.f,0.f,0.f};

    s16x8 qfr0, qfr1;
    MKQFR(qfr0, qbase + col)
    MKQFR(qfr1, qbase + 32 + col)

    const int ldsb = hi * CH + col;

    float run0 = __builtin_inff(), run1 = __builtin_inff();
    STAGE(c0, 0);
    __syncthreads();
    int cur = 0;
    for (int c = c0; c < c1; ++c) {
        if (c + 1 < c1) STAGE(c + 1, cur ^ 1);
        float cm0 = __builtin_inff(), cm1 = __builtin_inff();
#pragma unroll
        for (int tp = 0; tp < CH / 32; ++tp) {
            const s16x8 pA = *(const s16x8*)&lds[cur][ldsb + tp * 32];
            const f32x16 a0 = __builtin_amdgcn_mfma_f32_32x32x16_bf16(pA, qfr0, zf, 0, 0, 0);
            cm0 = fminf(cm0, fold16(a0));
            const f32x16 a1 = __builtin_amdgcn_mfma_f32_32x32x16_bf16(pA, qfr1, zf, 0, 0, 0);
            cm1 = fminf(cm1, fold16(a1));
        }
        // combine hi-halves (point rows 0-15 vs 16-31) -> true chunk min
        cm0 = fminf(cm0, __shfl_xor(cm0, 32, 64));
        cm1 = fminf(cm1, __shfl_xor(cm1, 32, 64));
        run0 = fminf(run0, cm0);
        run1 = fminf(run1, cm1);
        if (l < 32) {
            // round-DOWN bf16 (truncate): stored <= true for cm>=0; negatives
            // (|cm|<=2e-3 from cancellation) round up by <=8e-6, covered by
            // the +1e-5 slack in flag_kernel's threshold.
            cmin16[(size_t)(qbase + col) * NCH + c]      =
                (uint16_t)(__float_as_uint(cm0) >> 16);
            cmin16[(size_t)(qbase + 32 + col) * NCH + c] =
                (uint16_t)(__float_as_uint(cm1) >> 16);
        }
        __syncthreads();
        cur ^= 1;
    }
    if (l < 32) {
        atomicMin(&mkey[qbase + col],      key32(run0));
        atomicMin(&mkey[qbase + 32 + col], key32(run1));
    }
}

// ===== flag: build compact (q,ch) candidate queue =====
__global__ __launch_bounds__(256) void flag_kernel(
    const uint32_t* __restrict__ mkey, const uint16_t* __restrict__ cmin16,
    uint32_t* __restrict__ queue, uint32_t* __restrict__ qcount)
{
    const int q = blockIdx.x * 256 + threadIdx.x;     // 0..BN-1
    const float thr = dec32(mkey[q]) + MARGIN + 1.0e-5f;
    const uint4* row = (const uint4*)(cmin16 + (size_t)q * NCH);
    uint32_t fl = 0;                                   // bitmask of flagged chunks
#pragma unroll
    for (int w = 0; w < 4; ++w) {
        const uint4 u = row[w];
        const uint32_t c[4] = {u.x, u.y, u.z, u.w};
#pragma unroll
        for (int j = 0; j < 4; ++j) {
            if (bff((uint16_t)(c[j] & 0xFFFF)) <= thr) fl |= 1u << (w * 8 + j * 2);
            if (bff((uint16_t)(c[j] >> 16))    <= thr) fl |= 1u << (w * 8 + j * 2 + 1);
        }
    }
    const int nfl = __popc(fl);
    uint32_t base = atomicAdd(qcount, (uint32_t)nfl);
    while (fl) {
        const int ch = __ffs(fl) - 1;
        fl &= fl - 1;
        if (base < QCAP) queue[base] = ((uint32_t)q << 5) | (uint32_t)ch;
        ++base;
    }
}

// ===== walk: one wave per queue entry; exact eval of 512 points =====
__global__ __launch_bounds__(256, 8) void walk_kernel(
    const float* __restrict__ Xp, const float4* __restrict__ y4,
    const uint32_t* __restrict__ queue, const uint32_t* __restrict__ qcount,
    unsigned long long* __restrict__ gkeys)
{
#pragma clang fp contract(off)
    const int lane = threadIdx.x & 63;
    const uint32_t wid = blockIdx.x * 4 + (threadIdx.x >> 6);
    const uint32_t nw  = gridDim.x * 4;
    const uint32_t cnt = min(*qcount, QCAP);

    for (uint32_t e = wid; e < cnt; e += nw) {
        const uint32_t entry = queue[e];
        const int q  = (int)(entry >> 5);
        const int ch = (int)(entry & 31);
        const int b  = q >> 14;

        const float* xp = Xp + (size_t)q * 3;
        const float qx0 = xp[0], qx1 = xp[1], qx2 = xp[2];
        const float qxs = (qx0 * qx0 + qx1 * qx1) + qx2 * qx2;  // np order

        const float4* yb = y4 + (size_t)b * NPTS + (size_t)ch * CH;
        unsigned long long best = ~0ull;
#pragma unroll
        for (int j = 0; j < CH / 64; ++j) {
            const int k = j * 64 + lane;
            const float4 yv = yb[k];
            // bit-exact reference chain (validated R2..R23)
            const float dd = (qxs - 2.0f * ((qx0 * yv.x + qx1 * yv.y) + qx2 * yv.z)) + yv.w;
            const unsigned long long key =
                ((unsigned long long)key32(dd) << 32) | (uint32_t)(ch * CH + k);
            if (key < best) best = key;
        }
#pragma unroll
        for (int m = 1; m <= 32; m <<= 1) {
            const unsigned long long o = __shfl_xor(best, m, 64);
            if (o < best) best = o;
        }
        if (lane == 0) atomicMin(&gkeys[q], best);
    }
}

// ---- final: gkeys -> (dist, idx) for one direction ----
__global__ __launch_bounds__(256) void writeout_k(
    const unsigned long long* __restrict__ gkeys, float* __restrict__ out, int dir)
{
    const size_t q = (size_t)blockIdx.x * 256 + threadIdx.x;   // 0..BN-1
    const unsigned long long m = gkeys[q];
    out[(size_t)dir * BN + q]       = dec32((uint32_t)(m >> 32));
    out[(size_t)(2 + dir) * BN + q] = (float)(uint32_t)(m & 0xFFFFFFFFu);
}

extern "C" void kernel_launch(void* const* d_in, const int* in_sizes, int n_in,
                              void* d_out, int out_size, void* d_ws, size_t ws_size,
                              hipStream_t stream) {
    const float* xyz1 = (const float*)d_in[0];
    const float* xyz2 = (const float*)d_in[1];
    float* out = (float*)d_out;

    // ws layout (15.5 MiB; ws >= 16 MiB proven by R22/R23 taking that branch):
    // enc 4M (aliased as queue after sweep1) | y4 2M | mkey 0.5M | cmin 8M |
    // gkeys 1M | qcount 256B
    char* base = (char*)d_ws;
    uint4*    enc    = (uint4*)base;
    uint32_t* queue  = (uint32_t*)base;                       // alias (post-sweep1)
    float4*   y4     = (float4*)(base + (size_t)4 * 1024 * 1024);
    uint32_t* mkey   = (uint32_t*)(base + (size_t)6 * 1024 * 1024);
    uint16_t* cmin16 = (uint16_t*)(base + (size_t)6 * 1024 * 1024 + 512 * 1024);
    unsigned long long* gkeys =
        (unsigned long long*)(base + (size_t)14 * 1024 * 1024 + 512 * 1024);
    uint32_t* qcount = (uint32_t*)(base + (size_t)15 * 1024 * 1024 + 512 * 1024);

    for (int dir = 0; dir < 2; ++dir) {
        const float* Xq = dir ? xyz2 : xyz1;   // queries
        const float* Yp = dir ? xyz1 : xyz2;   // points

        hipMemsetAsync(mkey, 0xFF, (size_t)BN * 4, stream);
        hipMemsetAsync(gkeys, 0xFF, (size_t)BN * 8, stream);
        hipMemsetAsync(qcount, 0, 256, stream);

        enc_kernel<<<BN / 256, 256, 0, stream>>>(Yp, enc, y4);
        nn_sweep1<<<1024, 256, 0, stream>>>(Xq, enc, mkey, cmin16);
        flag_kernel<<<BN / 256, 256, 0, stream>>>(mkey, cmin16, queue, qcount);
        walk_kernel<<<2048, 256, 0, stream>>>(Xq, y4, queue, qcount, gkeys);
        writeout_k<<<BN / 256, 256, 0, stream>>>(gkeys, out, dir);
    }
}